// Round 6
// baseline (612.838 us; speedup 1.0000x reference)
//
#include <hip/hip_runtime.h>
#include <math.h>
#include <stdint.h>

constexpr int B = 2, S = 4096, D = 1024, H = 16, DK = 64;
constexpr int M_TOT = B * S; // 8192

typedef __attribute__((ext_vector_type(8))) short bf16x8;
typedef __attribute__((ext_vector_type(4))) float f32x4;
typedef unsigned short u16;

// fp32 -> bf16 round-to-nearest-even (manual, always correct)
__device__ inline u16 f2bf(float f) {
    uint32_t u = __builtin_bit_cast(uint32_t, f);
    u += 0x7fffu + ((u >> 16) & 1u);
    return (u16)(u >> 16);
}

// fp32 -> bf16 via native __bf16
__device__ inline u16 f2bf_hw(float f) {
    __bf16 h = (__bf16)f;
    return __builtin_bit_cast(u16, h);
}

// async global->LDS, 16B per lane. lds base must be wave-uniform.
__device__ inline void gl2lds16(const void* g, void* l) {
    __builtin_amdgcn_global_load_lds((const __attribute__((address_space(1))) void*)g,
                                     (__attribute__((address_space(3))) void*)l, 16, 0, 0);
}

// ---------------------------------------------------------------------------
// fp32 -> bf16 conversion; blockIdx.y selects tensor.
// ---------------------------------------------------------------------------
__global__ __launch_bounds__(256) void conv_bf16(const float* __restrict__ s0, const float* __restrict__ s1,
                                                 const float* __restrict__ s2, const float* __restrict__ s3,
                                                 u16* __restrict__ d0, u16* __restrict__ d1,
                                                 u16* __restrict__ d2, u16* __restrict__ d3, int n) {
    const float* s; u16* d;
    switch (blockIdx.y) {
        case 0: s = s0; d = d0; break;
        case 1: s = s1; d = d1; break;
        case 2: s = s2; d = d2; break;
        default: s = s3; d = d3; break;
    }
    const int i = (blockIdx.x * 256 + threadIdx.x) * 4;
    if (i < n) {
        float4 v = *(const float4*)(s + i);
        ushort4 o;
        o.x = f2bf(v.x); o.y = f2bf(v.y); o.z = f2bf(v.z); o.w = f2bf(v.w);
        *(ushort4*)(d + i) = o;
    }
}

// int32 mask [S,S] -> bitmask, bit c of u64 word (q*64+t) = mask[q][t*64+c]
__global__ __launch_bounds__(256) void mask_pack(const int* __restrict__ m, uint32_t* __restrict__ out) {
    const int i = blockIdx.x * 256 + threadIdx.x;  // one u32 = 32 keys
    const int base = i * 32;
    uint32_t b = 0;
#pragma unroll
    for (int j = 0; j < 32; ++j) b |= (m[base + j] != 0 ? 1u : 0u) << j;
    out[i] = b;
}

// ---------------------------------------------------------------------------
// GEMM core: Y = oscale * X W^T. 128x128 tile, BK=64, m97 pattern.
// ---------------------------------------------------------------------------
template <typename OutT>
__device__ inline void gemm_core(const u16* __restrict__ X, const u16* __restrict__ Wm,
                                 OutT* __restrict__ Y, int i0, int j0, int N, int K,
                                 float oscale, u16* As, u16* Bs) {
    const int tid = threadIdx.x;
    const int lane = tid & 63;
    const int wave = tid >> 6;
    const int l15 = lane & 15;
    const int quad = lane >> 4;
    const int wm = wave & 1, wn = wave >> 1;
    const int lr = lane >> 3;        // row within 8-row chunk
    const int lc = (lane & 7) * 8;   // k offset within 64

    f32x4 acc[4][4];
#pragma unroll
    for (int a = 0; a < 4; ++a)
#pragma unroll
        for (int b2 = 0; b2 < 4; ++b2) acc[a][b2] = (f32x4){0.f, 0.f, 0.f, 0.f};

    for (int k0 = 0; k0 < K; k0 += 64) {
#pragma unroll
        for (int c = 0; c < 4; ++c) {
            const int ch = wave * 4 + c;          // 0..15
            const int row = ch * 8 + lr;          // 0..127
            gl2lds16(X + (size_t)(i0 + row) * K + k0 + lc, &As[ch * 512]);
            gl2lds16(Wm + (size_t)(j0 + row) * K + k0 + lc, &Bs[ch * 512]);
        }
        __syncthreads();
        bf16x8 af[4][2];
#pragma unroll
        for (int mt = 0; mt < 4; ++mt)
#pragma unroll
            for (int ks = 0; ks < 2; ++ks)
                af[mt][ks] = *(const bf16x8*)&As[(wm * 64 + mt * 16 + l15) * 64 + ks * 32 + quad * 8];
#pragma unroll
        for (int nt = 0; nt < 4; ++nt) {
#pragma unroll
            for (int ks = 0; ks < 2; ++ks) {
                bf16x8 bfr = *(const bf16x8*)&Bs[(wn * 64 + nt * 16 + l15) * 64 + ks * 32 + quad * 8];
#pragma unroll
                for (int mt = 0; mt < 4; ++mt)
                    acc[mt][nt] = __builtin_amdgcn_mfma_f32_16x16x32_bf16(af[mt][ks], bfr, acc[mt][nt], 0, 0, 0);
            }
        }
        __syncthreads();
    }
#pragma unroll
    for (int mt = 0; mt < 4; ++mt) {
#pragma unroll
        for (int r = 0; r < 4; ++r) {
            const int gi = i0 + wm * 64 + mt * 16 + quad * 4 + r;
#pragma unroll
            for (int nt = 0; nt < 4; ++nt) {
                const int gj = j0 + wn * 64 + nt * 16 + l15;
                const float v = acc[mt][nt][r] * oscale;
                if constexpr (sizeof(OutT) == 2) {
                    Y[(size_t)gi * N + gj] = (OutT)f2bf(v);
                } else {
                    Y[(size_t)gi * N + gj] = v;
                }
            }
        }
    }
}

// Batched Q/K/V projections: z=0: Qf = qb wq^T (scaled), z=1: Kf = kb wk^T,
// z=2: Vtf = wvb vb^T  (i.e. V^T, [D][M_TOT]).
__global__ __launch_bounds__(256) void proj3(const u16* __restrict__ X0, const u16* __restrict__ X1,
                                             const u16* __restrict__ X2, const u16* __restrict__ W0,
                                             const u16* __restrict__ W1, const u16* __restrict__ W2,
                                             u16* __restrict__ Y0, u16* __restrict__ Y1,
                                             u16* __restrict__ Y2, float s0) {
    __shared__ u16 As[128 * 64];
    __shared__ u16 Bs[128 * 64];
    const int z = blockIdx.y;
    const u16 *X, *W;
    u16* Y;
    float osc = 1.0f;
    if (z == 0) { X = X0; W = W0; Y = Y0; osc = s0; }
    else if (z == 1) { X = X1; W = W1; Y = Y1; }
    else { X = X2; W = W2; Y = Y2; }
    const int MB_ = (z == 2) ? 8 : 64;              // M/128
    const int N = (z == 2) ? M_TOT : D;
    const int bx = blockIdx.x;
    const int i0 = (bx % MB_) * 128;
    const int j0 = (bx / MB_) * 128;
    gemm_core<u16>(X, W, Y, i0, j0, N, D, osc, As, Bs);
}

// Output projection (fp32 out).
__global__ __launch_bounds__(256) void gemm_out(const u16* __restrict__ X, const u16* __restrict__ Wm,
                                                float* __restrict__ Y) {
    __shared__ u16 As[128 * 64];
    __shared__ u16 Bs[128 * 64];
    gemm_core<float>(X, Wm, Y, blockIdx.x * 128, blockIdx.y * 128, D, D, 1.0f, As, Bs);
}

// ---------------------------------------------------------------------------
// Flash attention, bf16 MFMA, static-shift softmax (p = exp2(s); shift
// cancels in 1/l; row sums via all-ones MFMA column).
// Grid: (S/256, B*H). 4 waves; each wave owns 64 q-rows (4 m-frags).
// K/V LDS XOR-swizzled; Ps stride 68 (conflict-free). K/V staging software-
// pipelined: next tile's global loads issue before current tile's compute.
// ---------------------------------------------------------------------------
__global__ __launch_bounds__(256) void attn_mfma(const u16* __restrict__ Qb, const u16* __restrict__ Kb,
                                                 const u16* __restrict__ Vt,
                                                 const uint64_t* __restrict__ mask64,
                                                 u16* __restrict__ ctx) {
    __shared__ u16 Ks[64 * 64];          // [key][dk], 8-col blocks XOR-swizzled
    __shared__ u16 Vs[64 * 64];          // [dv][key], 8-col blocks XOR-swizzled
    __shared__ u16 Ps[4][64 * 68];       // per-wave P tile (64 q-rows), stride 68
    const int tid = threadIdx.x;
    const int lane = tid & 63;
    const int wave = tid >> 6;
    const int l15 = lane & 15;
    const int quad = lane >> 4;
    const int q0 = blockIdx.x * 256;
    const int bh = blockIdx.y;
    const int bb = bh >> 4, hh = bh & 15;
    const int mbase = bb * S;
    const int e0 = hh * DK;
    const int r7 = l15 & 7;

    // staging mapping: thread -> (row 0..63, col-block 0..3 [+4])
    const int srow = tid >> 2;
    const int scb = tid & 3;

    // Q fragments: 4 m-tiles of 16 rows (Q pre-scaled by 0.125*log2e).
    bf16x8 aq[4][2];
#pragma unroll
    for (int mi = 0; mi < 4; ++mi) {
        const u16* qrow = Qb + (size_t)(mbase + q0 + wave * 64 + mi * 16 + l15) * D + e0;
        aq[mi][0] = *(const bf16x8*)(qrow + quad * 8);
        aq[mi][1] = *(const bf16x8*)(qrow + 32 + quad * 8);
    }

    f32x4 O[4][4];
    f32x4 Ol[4];
#pragma unroll
    for (int mi = 0; mi < 4; ++mi) {
        Ol[mi] = (f32x4){0.f, 0.f, 0.f, 0.f};
#pragma unroll
        for (int dt = 0; dt < 4; ++dt) O[mi][dt] = (f32x4){0.f, 0.f, 0.f, 0.f};
    }

    bf16x8 ONES;
#pragma unroll
    for (int i = 0; i < 8; ++i) ONES[i] = (short)0x3F80;  // bf16 1.0

    const uint64_t* mrow[4];
#pragma unroll
    for (int mi = 0; mi < 4; ++mi)
        mrow[mi] = mask64 + (size_t)(q0 + wave * 64 + mi * 16 + quad * 4) * (S / 64);

    // Prefetch tile 0 staging data into registers.
    bf16x8 kreg[2], vreg[2];
#pragma unroll
    for (int it = 0; it < 2; ++it) {
        const int cb = scb + it * 4;
        kreg[it] = *(const bf16x8*)(Kb + (size_t)(mbase + srow) * D + e0 + cb * 8);
        vreg[it] = *(const bf16x8*)(Vt + (size_t)(e0 + srow) * M_TOT + mbase + cb * 8);
    }

    constexpr int NT = S / 64;
    for (int kt = 0; kt < NT; ++kt) {
        // Store staged regs to LDS (swizzled).
#pragma unroll
        for (int it = 0; it < 2; ++it) {
            const int cb = scb + it * 4;
            const int phys = cb ^ (srow & 7);
            *(bf16x8*)&Ks[srow * 64 + phys * 8] = kreg[it];
            *(bf16x8*)&Vs[srow * 64 + phys * 8] = vreg[it];
        }
        __syncthreads();

        // Issue next tile's global loads early (latency overlaps compute).
        if (kt + 1 < NT) {
            const int kb = (kt + 1) * 64;
#pragma unroll
            for (int it = 0; it < 2; ++it) {
                const int cb = scb + it * 4;
                kreg[it] = *(const bf16x8*)(Kb + (size_t)(mbase + kb + srow) * D + e0 + cb * 8);
                vreg[it] = *(const bf16x8*)(Vt + (size_t)(e0 + srow) * M_TOT + mbase + kb + cb * 8);
            }
        }

        // K B-fragments, shared by all 4 m-tiles.
        bf16x8 kf[4][2];
#pragma unroll
        for (int nt = 0; nt < 4; ++nt) {
            kf[nt][0] = *(const bf16x8*)&Ks[(nt * 16 + l15) * 64 + (quad ^ r7) * 8];
            kf[nt][1] = *(const bf16x8*)&Ks[(nt * 16 + l15) * 64 + ((quad + 4) ^ r7) * 8];
        }

        u16* pw = &Ps[wave][0];
#pragma unroll
        for (int mi = 0; mi < 4; ++mi) {
            f32x4 sa[4];
#pragma unroll
            for (int nt = 0; nt < 4; ++nt) {
                f32x4 c = {0.f, 0.f, 0.f, 0.f};
                c = __builtin_amdgcn_mfma_f32_16x16x32_bf16(aq[mi][0], kf[nt][0], c, 0, 0, 0);
                c = __builtin_amdgcn_mfma_f32_16x16x32_bf16(aq[mi][1], kf[nt][1], c, 0, 0, 0);
                sa[nt] = c;
            }
            uint32_t mlo[4], mhi[4];
#pragma unroll
            for (int r = 0; r < 4; ++r) {
                const uint64_t sh = mrow[mi][(size_t)r * (S / 64) + kt] >> l15;
                mlo[r] = (uint32_t)sh;
                mhi[r] = (uint32_t)(sh >> 32);
            }
#pragma unroll
            for (int nt = 0; nt < 4; ++nt) {
#pragma unroll
                for (int r = 0; r < 4; ++r) {
                    const uint32_t w32 = (nt < 2) ? mlo[r] : mhi[r];
                    const uint32_t bit = (w32 >> ((nt & 1) * 16)) & 1u;
                    float p = __builtin_amdgcn_exp2f(sa[nt][r]);
                    p = bit ? p : 0.f;
                    pw[(mi * 16 + quad * 4 + r) * 68 + nt * 16 + l15] = f2bf_hw(p);
                }
            }
        }

        // V B-fragments, shared by all m-tiles.
        bf16x8 bv[4][2];
#pragma unroll
        for (int dt = 0; dt < 4; ++dt) {
            bv[dt][0] = *(const bf16x8*)&Vs[(dt * 16 + l15) * 64 + (quad ^ r7) * 8];
            bv[dt][1] = *(const bf16x8*)&Vs[(dt * 16 + l15) * 64 + ((quad + 4) ^ r7) * 8];
        }

#pragma unroll
        for (int mi = 0; mi < 4; ++mi) {
            const bf16x8 ap0 = *(const bf16x8*)&pw[(mi * 16 + l15) * 68 + quad * 8];
            const bf16x8 ap1 = *(const bf16x8*)&pw[(mi * 16 + l15) * 68 + 32 + quad * 8];
            Ol[mi] = __builtin_amdgcn_mfma_f32_16x16x32_bf16(ap0, ONES, Ol[mi], 0, 0, 0);
            Ol[mi] = __builtin_amdgcn_mfma_f32_16x16x32_bf16(ap1, ONES, Ol[mi], 0, 0, 0);
#pragma unroll
            for (int dt = 0; dt < 4; ++dt) {
                O[mi][dt] = __builtin_amdgcn_mfma_f32_16x16x32_bf16(ap0, bv[dt][0], O[mi][dt], 0, 0, 0);
                O[mi][dt] = __builtin_amdgcn_mfma_f32_16x16x32_bf16(ap1, bv[dt][1], O[mi][dt], 0, 0, 0);
            }
        }
        __syncthreads();
    }

    // Epilogue: normalize by row sum, write ctx bf16 [B,S,D].
#pragma unroll
    for (int mi = 0; mi < 4; ++mi) {
#pragma unroll
        for (int r = 0; r < 4; ++r) {
            const float inv = 1.f / Ol[mi][r];
            const int gm = mbase + q0 + wave * 64 + mi * 16 + quad * 4 + r;
#pragma unroll
            for (int dt = 0; dt < 4; ++dt)
                ctx[(size_t)gm * D + e0 + dt * 16 + l15] = f2bf(O[mi][dt][r] * inv);
        }
    }
}

// ---------------------------------------------------------------------------
extern "C" void kernel_launch(void* const* d_in, const int* in_sizes, int n_in,
                              void* d_out, int out_size, void* d_ws, size_t ws_size,
                              hipStream_t stream) {
    (void)in_sizes; (void)n_in; (void)out_size; (void)ws_size;
    const float* q = (const float*)d_in[0];
    const float* k = (const float*)d_in[1];
    const float* v = (const float*)d_in[2];
    const int* msk = (const int*)d_in[3];
    const float* w_q = (const float*)d_in[4];
    const float* w_k = (const float*)d_in[5];
    const float* w_v = (const float*)d_in[6];
    const float* w_o = (const float*)d_in[7];
    float* out = (float*)d_out;

    const size_t MB = 1u << 20;
    char* w = (char*)d_ws;
    u16* qb   = (u16*)(w + 0 * MB);     // 16 MB
    u16* kb   = (u16*)(w + 16 * MB);    // 16 MB
    u16* vb   = (u16*)(w + 32 * MB);    // 16 MB
    u16* wqb  = (u16*)(w + 48 * MB);    // 2 MB
    u16* wkb  = (u16*)(w + 50 * MB);    // 2 MB
    u16* wvb  = (u16*)(w + 52 * MB);    // 2 MB
    u16* wob  = (u16*)(w + 54 * MB);    // 2 MB
    uint64_t* maskb = (uint64_t*)(w + 56 * MB);  // 2 MB
    u16* Qf   = (u16*)(w + 58 * MB);    // 16 MB
    u16* Kf   = (u16*)(w + 74 * MB);    // 16 MB
    u16* Vtf  = (u16*)(w + 90 * MB);    // 16 MB
    u16* ctxb = (u16*)(w + 106 * MB);   // 16 MB

    // scale folded into Q projection: (1/sqrt(DK)) * log2(e)
    const float SCL2 = 0.18033688011112042f;

    dim3 blk(256);
    conv_bf16<<<dim3(8192, 3), blk, 0, stream>>>(q, k, v, q, qb, kb, vb, qb, M_TOT * D);
    conv_bf16<<<dim3(1024, 4), blk, 0, stream>>>(w_q, w_k, w_v, w_o, wqb, wkb, wvb, wob, D * D);
    mask_pack<<<dim3(S * S / 32 / 256), blk, 0, stream>>>(msk, (uint32_t*)maskb);

    // Batched projections: z=0 Q (scaled), z=1 K, z=2 V^T.
    proj3<<<dim3(512, 3), blk, 0, stream>>>(qb, kb, wvb, wqb, wkb, vb, Qf, Kf, Vtf, SCL2);

    attn_mfma<<<dim3(S / 256, B * H), blk, 0, stream>>>(Qf, Kf, Vtf, maskb, ctxb);

    gemm_out<<<dim3(M_TOT / 128, D / 128), blk, 0, stream>>>(ctxb, wob, out);
}